// Round 15
// baseline (207.873 us; speedup 1.0000x reference)
//
#include <hip/hip_runtime.h>

typedef __attribute__((ext_vector_type(4))) float f32x4;
typedef __attribute__((ext_vector_type(8))) short bf16x8;

__device__ __forceinline__ float bf2f(unsigned short u) {
  union { unsigned int i; float f; } x; x.i = ((unsigned int)u) << 16; return x.f;
}
__device__ __forceinline__ unsigned short f2bf(float f) {
  union { float f; unsigned int i; } x; x.f = f;
  unsigned int r = (x.i + 0x7FFFu + ((x.i >> 16) & 1u)) >> 16;
  return (unsigned short)r;
}

#define BARX __builtin_amdgcn_s_barrier()
#define VM0  asm volatile("s_waitcnt vmcnt(0)" ::: "memory")
#define GLD(gsrc, ldsoff)                                                        \
  __builtin_amdgcn_global_load_lds(                                              \
      (const __attribute__((address_space(1))) void*)(gsrc),                     \
      (__attribute__((address_space(3))) void*)&lds[ldsoff], 16, 0, 0)

// ---------------- convert f32 -> bf16 ----------------
__global__ __launch_bounds__(256) void cvt_f2b(const float* __restrict__ src,
                                               unsigned short* __restrict__ dst, long n4) {
  long i = (long)blockIdx.x * 256 + threadIdx.x;
  long stride = (long)gridDim.x * 256;
  for (; i < n4; i += stride) {
    float4 v = *(const float4*)&src[i * 4];
    ushort4 o;
    o.x = f2bf(v.x); o.y = f2bf(v.y); o.z = f2bf(v.z); o.w = f2bf(v.w);
    *(ushort4*)&dst[i * 4] = o;
  }
}

// ------- fused W transpose: z selects Wq/Wk/Wv; dst = Wt + z*1M, [cols][rows] bf16 -------
__global__ __launch_bounds__(256) void transpose_w(const float* __restrict__ Wq,
                                                   const float* __restrict__ Wk,
                                                   const float* __restrict__ Wv,
                                                   unsigned short* __restrict__ dst) {
  __shared__ float t[32][33];
  const float* src = (blockIdx.z == 0) ? Wq : (blockIdx.z == 1) ? Wk : Wv;
  unsigned short* d = dst + (long)blockIdx.z * 1024 * 1024;
  int bx = blockIdx.x * 32, by = blockIdx.y * 32;
  int tx = threadIdx.x, ty = threadIdx.y;
#pragma unroll
  for (int k = 0; k < 4; ++k)
    t[ty + 8 * k][tx] = src[(long)(by + ty + 8 * k) * 1024 + bx + tx];
  __syncthreads();
#pragma unroll
  for (int k = 0; k < 4; ++k)
    d[(long)(bx + ty + 8 * k) * 1024 + by + tx] = f2bf(t[tx][ty + 8 * k]);
}

// ============ 64x128 NT GEMM, 2 waves/block, single 24KiB buffer, 6 blocks/CU =============
// Per-wave work IDENTICAL to r10/r14 (C 64x64, 16 ds_read_b128 + 32 MFMA per K-tile, same
// registers) -- only the block envelope shrinks, raising co-residency 2.3 -> ~6 blocks/CU
// (LDS 24KiB x 6 = 144 <= 160; regs ~156 unified -> 3 waves/SIMD = 12 waves = 6 blocks).
// The m97/m114 cross-block overlap is the only mechanism that ever paid in this session;
// this scales it. Barriers now span 2 waves (cheaper). Staging bytes/FLOP x1.5 (benign at
// ~600 GB/s). Per K-tile: {12 GLD; vmcnt(0); bar; ds_reads + 32 MFMA; bar}.
// Swizzle (verified r4-r14, conflicts=0): 16B-group g of row r stored at g^(r&7).
// MODE 0 (proj): cols<2048 -> bf16(acc+bias) into QK (ld 2080); cols>=2048 (wave-uniform)
//   -> V written TRANSPOSED into VT[d][s] (ld 2064), bias pre-added (r14-verified).
// MODE 1 (scores): bf16(exp(acc*scale)).  MODE 2 (PV): f32(acc/rowsum(A)) via mfma(a,ones),
//   lane-local (r8/r10-verified; both waves read the same A rows -> each holds full es).
template <int MODE>
__global__ __launch_bounds__(128, 2) void gemmo(const unsigned short* __restrict__ Ap_,
                                                const unsigned short* __restrict__ Bp_,
                                                void* __restrict__ Cv,
                                                void* __restrict__ vtv,
                                                const float* __restrict__ q_,
                                                const float* __restrict__ k_,
                                                const float* __restrict__ v_,
                                                int Kd, int lda, int ldb, int ldc, float scale,
                                                long sA, long sB, long sC) {
  __shared__ unsigned short lds[12288];  // 24 KiB: A[64][64] @0, B[128][64] @4096 (elems)
  int bx, by, bz;
  if (MODE == 2) {
    // T1 bijective XCD swizzle: 1024 blocks = 8 XCDs x 128; grid (32,8,4) x-fastest
    const int flat = blockIdx.x;
    const int nid = ((flat & 7) << 7) | (flat >> 3);
    bx = nid & 31; by = (nid >> 5) & 7; bz = nid >> 8;
  } else {
    bx = blockIdx.x; by = blockIdx.y; bz = blockIdx.z;
  }
  const int tid = threadIdx.x;
  const int m0 = bx * 64, n0 = by * 128;
  const int lane = tid & 63, wave = tid >> 6;  // wave 0/1 splits N
  // staging map (global source pre-swizzled; LDS dest linear)
  const int rr = tid >> 3;                       // 0..15
  const int cSrc = ((tid & 7) ^ (rr & 7)) << 3;  // swizzled source col (elems)
  // fragment-read map (per-thread-constant swizzle terms)
  const int lc = lane & 15, lr = lane >> 4;
  const int x0 = (lc & 4) << 3;
  const int x1 = 32 ^ x0;
  const int klo = (lr << 3) ^ ((lc & 3) << 3);
  const int aoff = lc * 64 + klo;                    // A rows 0..63 (shared by both waves)
  const int boff = 4096 + (wave * 64 + lc) * 64 + klo;
  const int NT = Kd >> 6;

  const unsigned short* pA = Ap_ + (long)bz * sA + (long)(m0 + rr) * lda + cSrc;
  const unsigned short* pB = Bp_ + (long)bz * sB + (long)(n0 + rr) * ldb + cSrc;
  const long a16 = (long)16 * lda, b16 = (long)16 * ldb;

  f32x4 acc[4][4] = {};
  f32x4 es[4] = {};
  bf16x8 ones;
#pragma unroll
  for (int j = 0; j < 8; ++j) ones[j] = (short)0x3F80;  // bf16 1.0

  for (int t = 0; t < NT; ++t) {
    // ---- stage tile t: A 4 rounds (16 rows each), B 8 rounds
#pragma unroll
    for (int j = 0; j < 4; ++j) GLD(pA + j * a16, j * 1024 + tid * 8);
#pragma unroll
    for (int j = 0; j < 8; ++j) GLD(pB + j * b16, 4096 + j * 1024 + tid * 8);
    VM0;
    BARX;
    // ---- sub-phase 1: bb(8 frags) + a0(4 frags), MFMA mi 0,1
    bf16x8 a0[2][2], a1[2][2], bb[4][2];
#pragma unroll
    for (int ni = 0; ni < 4; ++ni) {
      bb[ni][0] = *(const bf16x8*)&lds[boff + ni * 1024 + x0];
      bb[ni][1] = *(const bf16x8*)&lds[boff + ni * 1024 + x1];
    }
#pragma unroll
    for (int mi = 0; mi < 2; ++mi) {
      a0[mi][0] = *(const bf16x8*)&lds[aoff + mi * 1024 + x0];
      a0[mi][1] = *(const bf16x8*)&lds[aoff + mi * 1024 + x1];
    }
    __builtin_amdgcn_s_setprio(1);
#pragma unroll
    for (int mi = 0; mi < 2; ++mi)
#pragma unroll
      for (int ni = 0; ni < 4; ++ni)
#pragma unroll
        for (int x = 0; x < 2; ++x)
          acc[mi][ni] = __builtin_amdgcn_mfma_f32_16x16x32_bf16(
              a0[mi][x], bb[ni][x], acc[mi][ni], 0, 0, 0);
    if (MODE == 2) {
#pragma unroll
      for (int mi = 0; mi < 2; ++mi)
#pragma unroll
        for (int x = 0; x < 2; ++x)
          es[mi] = __builtin_amdgcn_mfma_f32_16x16x32_bf16(a0[mi][x], ones, es[mi], 0, 0, 0);
    }
    __builtin_amdgcn_s_setprio(0);
    // ---- sub-phase 2: a1(4 frags), MFMA mi 2,3
#pragma unroll
    for (int mi = 0; mi < 2; ++mi) {
      a1[mi][0] = *(const bf16x8*)&lds[aoff + 2048 + mi * 1024 + x0];
      a1[mi][1] = *(const bf16x8*)&lds[aoff + 2048 + mi * 1024 + x1];
    }
    __builtin_amdgcn_s_setprio(1);
#pragma unroll
    for (int mi = 0; mi < 2; ++mi)
#pragma unroll
      for (int ni = 0; ni < 4; ++ni)
#pragma unroll
        for (int x = 0; x < 2; ++x)
          acc[2 + mi][ni] = __builtin_amdgcn_mfma_f32_16x16x32_bf16(
              a1[mi][x], bb[ni][x], acc[2 + mi][ni], 0, 0, 0);
    if (MODE == 2) {
#pragma unroll
      for (int mi = 0; mi < 2; ++mi)
#pragma unroll
        for (int x = 0; x < 2; ++x)
          es[2 + mi] = __builtin_amdgcn_mfma_f32_16x16x32_bf16(a1[mi][x], ones, es[2 + mi], 0, 0, 0);
    }
    __builtin_amdgcn_s_setprio(0);
    BARX;  // all waves done reading -> next tile's stage may overwrite
    pA += 64; pB += 64;
  }

  // ---- epilogue: C/D map col=lane&15, row=4*(lane>>4)+r; acc[mi] = row-block mi*16
  const int r0 = m0 + lr * 4;
  const int c0 = n0 + wave * 64 + lc;
  if (MODE == 2) {
    float* O = (float*)Cv + (long)bz * sC;
#pragma unroll
    for (int mi = 0; mi < 4; ++mi)
#pragma unroll
      for (int r = 0; r < 4; ++r) {
        const float iv = 1.0f / es[mi][r];  // rowsum of row r0+mi*16+r, lane-local
#pragma unroll
        for (int ni = 0; ni < 4; ++ni)
          O[(long)(r0 + mi * 16 + r) * ldc + (c0 + ni * 16)] = acc[mi][ni][r] * iv;
      }
  } else if (MODE == 0 && n0 >= 2048) {
    // ---- V part: write transposed into VT[b][d][s] (ld 2064), bias pre-added
    unsigned short* VTp = (unsigned short*)vtv + (long)(m0 >> 11) * 1024 * 2064;
    const int sl = (m0 & 2047) + lr * 4;  // token index within batch
#pragma unroll
    for (int ni = 0; ni < 4; ++ni) {
      const int d = c0 - 2048 + ni * 16;
      const float bv = v_[d];
#pragma unroll
      for (int mi = 0; mi < 4; ++mi)
#pragma unroll
        for (int r = 0; r < 4; ++r)
          VTp[(long)d * 2064 + (sl + mi * 16 + r)] = f2bf(acc[mi][ni][r] + bv);
    }
  } else {
    unsigned short* C = (unsigned short*)Cv + (long)bz * sC;
#pragma unroll
    for (int ni = 0; ni < 4; ++ni) {
      const int col = c0 + ni * 16;
      float bv = 0.0f;
      if (MODE == 0) bv = (col < 1024) ? q_[col] : k_[col - 1024];
#pragma unroll
      for (int mi = 0; mi < 4; ++mi)
#pragma unroll
        for (int r = 0; r < 4; ++r) {
          float val = acc[mi][ni][r];
          val = (MODE == 0) ? (val + bv) : __expf(val * scale);
          C[(long)(r0 + mi * 16 + r) * ldc + col] = f2bf(val);
        }
    }
  }
}

extern "C" void kernel_launch(void* const* d_in, const int* in_sizes, int n_in,
                              void* d_out, int out_size, void* d_ws, size_t ws_size,
                              hipStream_t stream) {
  const float* x  = (const float*)d_in[0];
  const float* Wq = (const float*)d_in[1];
  const float* bq = (const float*)d_in[2];
  const float* Wk = (const float*)d_in[3];
  const float* bk = (const float*)d_in[4];
  const float* Wv = (const float*)d_in[5];
  const float* bv = (const float*)d_in[6];
  float* out = (float*)d_out;

  const int Bb = 4, S = 2048, D = 1024;
  const long MS = (long)Bb * S;  // 8192
  const int LDQ = 2080;          // QK ld (4160 B, breaks 4 KB aliasing)
  const int LDP = 2064;          // E and VT ld

  // ---- workspace layout (liveness-packed, r14-verified) ----
  char* ws = (char*)d_ws;
  unsigned short* xb = (unsigned short*)(ws);                  // [0,16M) x bf16
  unsigned short* Wt = (unsigned short*)(ws + (16L << 20));    // [16M,22M) [3072][1024]
  unsigned short* QK = (unsigned short*)(ws + (33L << 20));    // [33M,66M) [8192][2080]
  unsigned short* VT = (unsigned short*)(ws + (66L << 20));    // [66M,83M) [4][1024][2064]
  unsigned short* Sc = (unsigned short*)(ws);                  // [0,33M) overlays dead xb+Wt

  // 1) x -> bf16
  cvt_f2b<<<2048, 256, 0, stream>>>(x, xb, MS * D / 4);

  // 2) W -> bf16 transposed, concatenated [3072][1024] (one fused launch)
  dim3 tb(32, 8);
  dim3 tg(D / 32, D / 32, 3);
  transpose_w<<<tg, tb, 0, stream>>>(Wq, Wk, Wv, Wt);

  // 3) fused QKV projection: Q,K -> QK (ld 2080); V -> VT transposed (fused epilogue)
  dim3 pgrid(MS / 64, 3072 / 128, 1);
  gemmo<0><<<pgrid, 128, 0, stream>>>(xb, Wt, QK, VT, bq, bk, bv,
                                      D, D, D, LDQ, 1.0f, 0, 0, 0);

  // 4) E = exp(Q @ K^T / 32), bf16 into Sc (ld 2064)
  dim3 sgrid(S / 64, S / 128, Bb);
  gemmo<1><<<sgrid, 128, 0, stream>>>(QK, QK + 1024, Sc, nullptr, nullptr, nullptr, nullptr,
                                      D, LDQ, LDQ, LDP, 1.0f / 32.0f,
                                      (long)S * LDQ, (long)S * LDQ, (long)S * LDP);

  // 5) out = (E @ V) / rowsum(E), fp32 — MFMA-fused denominator, XCD swizzle (1024 blocks)
  gemmo<2><<<1024, 128, 0, stream>>>(Sc, VT, out, nullptr, nullptr, nullptr, nullptr,
                                     2048, LDP, LDP, D, 1.0f,
                                     (long)S * LDP, (long)D * LDP, (long)S * D);
}

// Round 16
// 168.498 us; speedup vs baseline: 1.2337x; 1.2337x over previous
//
#include <hip/hip_runtime.h>

typedef __attribute__((ext_vector_type(4))) float f32x4;
typedef __attribute__((ext_vector_type(8))) short bf16x8;

__device__ __forceinline__ float bf2f(unsigned short u) {
  union { unsigned int i; float f; } x; x.i = ((unsigned int)u) << 16; return x.f;
}
__device__ __forceinline__ unsigned short f2bf(float f) {
  union { float f; unsigned int i; } x; x.f = f;
  unsigned int r = (x.i + 0x7FFFu + ((x.i >> 16) & 1u)) >> 16;
  return (unsigned short)r;
}

#define BARX __builtin_amdgcn_s_barrier()
#define VM0  asm volatile("s_waitcnt vmcnt(0)" ::: "memory")
#define GLD(gsrc, ldsoff)                                                        \
  __builtin_amdgcn_global_load_lds(                                              \
      (const __attribute__((address_space(1))) void*)(gsrc),                     \
      (__attribute__((address_space(3))) void*)&lds[ldsoff], 16, 0, 0)

// ---------------- convert f32 -> bf16 ----------------
__global__ __launch_bounds__(256) void cvt_f2b(const float* __restrict__ src,
                                               unsigned short* __restrict__ dst, long n4) {
  long i = (long)blockIdx.x * 256 + threadIdx.x;
  long stride = (long)gridDim.x * 256;
  for (; i < n4; i += stride) {
    float4 v = *(const float4*)&src[i * 4];
    ushort4 o;
    o.x = f2bf(v.x); o.y = f2bf(v.y); o.z = f2bf(v.z); o.w = f2bf(v.w);
    *(ushort4*)&dst[i * 4] = o;
  }
}

// ------- fused W transpose: z selects Wq/Wk/Wv; dst = Wt + z*1M, [cols][rows] bf16 -------
__global__ __launch_bounds__(256) void transpose_w(const float* __restrict__ Wq,
                                                   const float* __restrict__ Wk,
                                                   const float* __restrict__ Wv,
                                                   unsigned short* __restrict__ dst) {
  __shared__ float t[32][33];
  const float* src = (blockIdx.z == 0) ? Wq : (blockIdx.z == 1) ? Wk : Wv;
  unsigned short* d = dst + (long)blockIdx.z * 1024 * 1024;
  int bx = blockIdx.x * 32, by = blockIdx.y * 32;
  int tx = threadIdx.x, ty = threadIdx.y;
#pragma unroll
  for (int k = 0; k < 4; ++k)
    t[ty + 8 * k][tx] = src[(long)(by + ty + 8 * k) * 1024 + bx + tx];
  __syncthreads();
#pragma unroll
  for (int k = 0; k < 4; ++k)
    d[(long)(bx + ty + 8 * k) * 1024 + by + tx] = f2bf(t[tx][ty + 8 * k]);
}

// =================== 128x128 NT GEMM, r10/r14 structure (measured session-best) ===========
// Single 32 KiB LDS buffer, 4 waves (2Mx2N), per-wave C 64x64, BK=64, 16x16x32 MFMA.
// Per K-tile: {8 global_load_lds; vmcnt(0); barrier; 16 ds_read_b128 + 32 MFMA; barrier}.
// Latency hidden by ~2-3 co-resident blocks/CU (m97/m114) -- the register file (arch ~76 +
// acc/es AGPRs) caps waves/SIMD at 3, so higher co-residency is unreachable (r15 measured).
// (256,2) bound: no spill (r9: (256,4) forced 64 VGPR -> 477 MB scratch traffic).
// Swizzle (verified r4-r14, SQ_LDS_BANK_CONFLICT=0): 16B-group g of row r stored at g^(r&7);
// stage source pre-swizzled; read XOR per-thread constant.
// MODE 0 (proj): cols<2048 -> bf16(acc+bias) into QK (ld 2080); cols>=2048 (wave-uniform)
//   -> V written TRANSPOSED into VT[d][s] (ld 2064), bias pre-added (fuses transpose_v).
// MODE 1 (scores): bf16(exp(acc*scale)) -- no max-shift, |scores/32| <~ 2.
// MODE 2 (PV): f32(acc/rowsum(A)); rowsum via mfma(a,ones) -- es[mi][r] lands in exactly
//   the lane owning acc row (C/D map), so the division is lane-local (verified r8/r10).
template <int MODE>
__global__ __launch_bounds__(256, 2) void gemmo(const unsigned short* __restrict__ Ap_,
                                                const unsigned short* __restrict__ Bp_,
                                                void* __restrict__ Cv,
                                                void* __restrict__ vtv,
                                                const float* __restrict__ q_,
                                                const float* __restrict__ k_,
                                                const float* __restrict__ v_,
                                                int Kd, int lda, int ldb, int ldc, float scale,
                                                long sA, long sB, long sC) {
  __shared__ unsigned short lds[16384];  // 32 KiB: A @0, B @8192 (elems)
  int bx, by, bz;
  if (MODE == 2) {
    // T1 bijective XCD swizzle: 512 blocks = 8 XCDs x 64; grid (16,8,4) x-fastest
    const int flat = blockIdx.x;
    const int nid = ((flat & 7) << 6) | (flat >> 3);
    bx = nid & 15; by = (nid >> 4) & 7; bz = nid >> 7;
  } else {
    bx = blockIdx.x; by = blockIdx.y; bz = blockIdx.z;
  }
  const int tid = threadIdx.x;
  const int m0 = bx * 128, n0 = by * 128;
  const int lane = tid & 63, wave = tid >> 6;
  const int wm = wave >> 1, wn = wave & 1;
  // staging map (global source pre-swizzled; LDS dest linear)
  const int rr = tid >> 3;                       // 0..31
  const int cSrc = ((tid & 7) ^ (rr & 7)) << 3;  // swizzled source col (elems)
  // fragment-read map (per-thread-constant swizzle terms)
  const int lc = lane & 15, lr = lane >> 4;
  const int x0 = (lc & 4) << 3;
  const int x1 = 32 ^ x0;
  const int klo = (lr << 3) ^ ((lc & 3) << 3);
  const int aoff = (wm * 64 + lc) * 64 + klo;
  const int boff = 8192 + (wn * 64 + lc) * 64 + klo;
  const int NT = Kd >> 6;

  const unsigned short* pA = Ap_ + (long)bz * sA + (long)(m0 + rr) * lda + cSrc;
  const unsigned short* pB = Bp_ + (long)bz * sB + (long)(n0 + rr) * ldb + cSrc;
  const long a32 = (long)32 * lda, b32 = (long)32 * ldb;

  f32x4 acc[4][4] = {};
  f32x4 es[4] = {};
  bf16x8 ones;
#pragma unroll
  for (int j = 0; j < 8; ++j) ones[j] = (short)0x3F80;  // bf16 1.0

  for (int t = 0; t < NT; ++t) {
    // ---- stage tile t into the single buffer
    GLD(pA, tid * 8);                  GLD(pA + a32, 2048 + tid * 8);
    GLD(pA + 2 * a32, 4096 + tid * 8); GLD(pA + 3 * a32, 6144 + tid * 8);
    GLD(pB, 8192 + tid * 8);           GLD(pB + b32, 10240 + tid * 8);
    GLD(pB + 2 * b32, 12288 + tid * 8); GLD(pB + 3 * b32, 14336 + tid * 8);
    VM0;
    BARX;
    // ---- sub-phase 1: bb(8 frags) + a0(4 frags), MFMA mi 0,1
    bf16x8 a0[2][2], a1[2][2], bb[4][2];
#pragma unroll
    for (int ni = 0; ni < 4; ++ni) {
      bb[ni][0] = *(const bf16x8*)&lds[boff + ni * 1024 + x0];
      bb[ni][1] = *(const bf16x8*)&lds[boff + ni * 1024 + x1];
    }
#pragma unroll
    for (int mi = 0; mi < 2; ++mi) {
      a0[mi][0] = *(const bf16x8*)&lds[aoff + mi * 1024 + x0];
      a0[mi][1] = *(const bf16x8*)&lds[aoff + mi * 1024 + x1];
    }
    __builtin_amdgcn_s_setprio(1);
#pragma unroll
    for (int mi = 0; mi < 2; ++mi)
#pragma unroll
      for (int ni = 0; ni < 4; ++ni)
#pragma unroll
        for (int x = 0; x < 2; ++x)
          acc[mi][ni] = __builtin_amdgcn_mfma_f32_16x16x32_bf16(
              a0[mi][x], bb[ni][x], acc[mi][ni], 0, 0, 0);
    if (MODE == 2) {
#pragma unroll
      for (int mi = 0; mi < 2; ++mi)
#pragma unroll
        for (int x = 0; x < 2; ++x)
          es[mi] = __builtin_amdgcn_mfma_f32_16x16x32_bf16(a0[mi][x], ones, es[mi], 0, 0, 0);
    }
    __builtin_amdgcn_s_setprio(0);
    // ---- sub-phase 2: a1(4 frags), MFMA mi 2,3
#pragma unroll
    for (int mi = 0; mi < 2; ++mi) {
      a1[mi][0] = *(const bf16x8*)&lds[aoff + 2048 + mi * 1024 + x0];
      a1[mi][1] = *(const bf16x8*)&lds[aoff + 2048 + mi * 1024 + x1];
    }
    __builtin_amdgcn_s_setprio(1);
#pragma unroll
    for (int mi = 0; mi < 2; ++mi)
#pragma unroll
      for (int ni = 0; ni < 4; ++ni)
#pragma unroll
        for (int x = 0; x < 2; ++x)
          acc[2 + mi][ni] = __builtin_amdgcn_mfma_f32_16x16x32_bf16(
              a1[mi][x], bb[ni][x], acc[2 + mi][ni], 0, 0, 0);
    if (MODE == 2) {
#pragma unroll
      for (int mi = 0; mi < 2; ++mi)
#pragma unroll
        for (int x = 0; x < 2; ++x)
          es[2 + mi] = __builtin_amdgcn_mfma_f32_16x16x32_bf16(a1[mi][x], ones, es[2 + mi], 0, 0, 0);
    }
    __builtin_amdgcn_s_setprio(0);
    BARX;  // all waves done reading -> next tile's stage may overwrite
    pA += 64; pB += 64;
  }

  // ---- epilogue: C/D map col=lane&15, row=4*(lane>>4)+r; acc[mi] = row-block mi*16
  const int r0 = m0 + wm * 64 + lr * 4;
  const int c0 = n0 + wn * 64 + lc;
  if (MODE == 2) {
    float* O = (float*)Cv + (long)bz * sC;
#pragma unroll
    for (int mi = 0; mi < 4; ++mi)
#pragma unroll
      for (int r = 0; r < 4; ++r) {
        const float iv = 1.0f / es[mi][r];  // rowsum of row r0+mi*16+r, lane-local
#pragma unroll
        for (int ni = 0; ni < 4; ++ni)
          O[(long)(r0 + mi * 16 + r) * ldc + (c0 + ni * 16)] = acc[mi][ni][r] * iv;
      }
  } else if (MODE == 0 && n0 >= 2048) {
    // ---- V part: write transposed into VT[b][d][s] (ld 2064), bias pre-added
    unsigned short* VTp = (unsigned short*)vtv + (long)(m0 >> 11) * 1024 * 2064;
    const int sl = (m0 & 2047) + wm * 64 + lr * 4;  // token index within batch
#pragma unroll
    for (int ni = 0; ni < 4; ++ni) {
      const int d = c0 - 2048 + ni * 16;
      const float bv = v_[d];
#pragma unroll
      for (int mi = 0; mi < 4; ++mi)
#pragma unroll
        for (int r = 0; r < 4; ++r)
          VTp[(long)d * 2064 + (sl + mi * 16 + r)] = f2bf(acc[mi][ni][r] + bv);
    }
  } else {
    unsigned short* C = (unsigned short*)Cv + (long)bz * sC;
#pragma unroll
    for (int ni = 0; ni < 4; ++ni) {
      const int col = c0 + ni * 16;
      float bv = 0.0f;
      if (MODE == 0) bv = (col < 1024) ? q_[col] : k_[col - 1024];
#pragma unroll
      for (int mi = 0; mi < 4; ++mi)
#pragma unroll
        for (int r = 0; r < 4; ++r) {
          float val = acc[mi][ni][r];
          val = (MODE == 0) ? (val + bv) : __expf(val * scale);
          C[(long)(r0 + mi * 16 + r) * ldc + col] = f2bf(val);
        }
    }
  }
}

extern "C" void kernel_launch(void* const* d_in, const int* in_sizes, int n_in,
                              void* d_out, int out_size, void* d_ws, size_t ws_size,
                              hipStream_t stream) {
  const float* x  = (const float*)d_in[0];
  const float* Wq = (const float*)d_in[1];
  const float* bq = (const float*)d_in[2];
  const float* Wk = (const float*)d_in[3];
  const float* bk = (const float*)d_in[4];
  const float* Wv = (const float*)d_in[5];
  const float* bv = (const float*)d_in[6];
  float* out = (float*)d_out;

  const int Bb = 4, S = 2048, D = 1024;
  const long MS = (long)Bb * S;  // 8192
  const int LDQ = 2080;          // QK ld (4160 B, breaks 4 KB aliasing)
  const int LDP = 2064;          // E and VT ld

  // ---- workspace layout (liveness-packed, r14-verified) ----
  char* ws = (char*)d_ws;
  unsigned short* xb = (unsigned short*)(ws);                  // [0,16M) x bf16
  unsigned short* Wt = (unsigned short*)(ws + (16L << 20));    // [16M,22M) [3072][1024]
  unsigned short* QK = (unsigned short*)(ws + (33L << 20));    // [33M,66M) [8192][2080]
  unsigned short* VT = (unsigned short*)(ws + (66L << 20));    // [66M,83M) [4][1024][2064]
  unsigned short* Sc = (unsigned short*)(ws);                  // [0,33M) overlays dead xb+Wt

  // 1) x -> bf16
  cvt_f2b<<<2048, 256, 0, stream>>>(x, xb, MS * D / 4);

  // 2) W -> bf16 transposed, concatenated [3072][1024] (one fused launch)
  dim3 tb(32, 8);
  dim3 tg(D / 32, D / 32, 3);
  transpose_w<<<tg, tb, 0, stream>>>(Wq, Wk, Wv, Wt);

  // 3) fused QKV projection: Q,K -> QK (ld 2080); V -> VT transposed (fused epilogue)
  dim3 pgrid(MS / 128, 3072 / 128, 1);
  gemmo<0><<<pgrid, 256, 0, stream>>>(xb, Wt, QK, VT, bq, bk, bv,
                                      D, D, D, LDQ, 1.0f, 0, 0, 0);

  // 4) E = exp(Q @ K^T / 32), bf16 into Sc (ld 2064)
  dim3 sgrid(S / 128, S / 128, Bb);
  gemmo<1><<<sgrid, 256, 0, stream>>>(QK, QK + 1024, Sc, nullptr, nullptr, nullptr, nullptr,
                                      D, LDQ, LDQ, LDP, 1.0f / 32.0f,
                                      (long)S * LDQ, (long)S * LDQ, (long)S * LDP);

  // 5) out = (E @ V) / rowsum(E), fp32 — MFMA-fused denominator, XCD swizzle (512 blocks)
  gemmo<2><<<512, 256, 0, stream>>>(Sc, VT, out, nullptr, nullptr, nullptr, nullptr,
                                    2048, LDP, LDP, D, 1.0f,
                                    (long)S * LDP, (long)D * LDP, (long)S * D);
}